// Round 7
// baseline (99.280 us; speedup 1.0000x reference)
//
#include <hip/hip_runtime.h>

// SlotAttention: B=8, L=256, D=256, K=64
// out[b,i,:] = concat(inputs[b,i,:], context[b,i,:])
// scores[b,i,j] = sum_k W2[k]*tanh(qi+kj); attn = softmax_j; ctx = attn @ inputs[b]
//
// Round-7 (3-kernel):
//  K1 proj: Eq = e^{2qi}, Ek = e^{2kj}  (tanh(q+k) = 1 - 2/(Eq*Ek+1))
//  K2 scores+softmax: T = sum_k w_k rcp(Eq*Ek+1); attn = softmax_j(-2T)
//     (W=sum w cancels by shift-invariance; |2T|<=~13 so no max-subtract).
//     Writes attn (8,256,256) to ws.
//  K3 context: tiled attn@X. Block = (b, 32-row i-tile, 32-col d-tile),
//     512 blocks (2/CU). Cuts phase-3 L2 traffic 128->32 MB vs round 6.

#define Bn 8
#define Ln 256
#define Dn 256
#define Kn 64
#define ROWS (Bn*Ln)       // 2048
#define IPB 4              // query rows per block in K2
#define ASTRIDE 260        // LDS stride for attn tile: %32==4 (conflict-free), %4==0 (b128)

// ---------------- K1: projection -> exp form ----------------
__global__ __launch_bounds__(128) void proj_kernel(
    const float* __restrict__ X,    // (2048,256)
    const float* __restrict__ W1,   // (64,512)
    float* __restrict__ QK)         // (2048,128)
{
    __shared__ float Xs[4 * 256];
    const int tid = threadIdx.x;
    const int r0 = blockIdx.x * 4;

    const float4* Xg4 = (const float4*)(X + r0 * Dn);
    float4* Xs4 = (float4*)Xs;
    #pragma unroll
    for (int idx = tid; idx < 256; idx += 128) Xs4[idx] = Xg4[idx];
    __syncthreads();

    const int k = tid & 63, half = tid >> 6;
    const float4* Wrow = (const float4*)(W1 + k * (2 * Dn) + half * Dn);
    float acc[4] = {0, 0, 0, 0};
    #pragma unroll 8
    for (int d4 = 0; d4 < 64; ++d4) {
        float4 w = Wrow[d4];
        #pragma unroll
        for (int r = 0; r < 4; ++r) {
            float4 x = ((const float4*)(Xs + r * Dn))[d4];  // uniform LDS broadcast
            float a = acc[r];
            a = fmaf(w.x, x.x, a);
            a = fmaf(w.y, x.y, a);
            a = fmaf(w.z, x.z, a);
            a = fmaf(w.w, x.w, a);
            acc[r] = a;
        }
    }
    #pragma unroll
    for (int r = 0; r < 4; ++r)
        QK[(r0 + r) * 128 + tid] = __expf(2.0f * acc[r]);   // Eq or Ek
}

// ---------------- K2: scores + softmax -> attn in ws ----------------
// grid = ROWS/IPB = 512 blocks, 256 threads; rows i0..i0+3 of batch b.
__global__ __launch_bounds__(256) void score_kernel(
    const float* __restrict__ QK,   // (2048,128) exp'd
    const float* __restrict__ W2,   // (64,)
    float* __restrict__ attn)       // (8,256,256)
{
    __shared__ float eq_s[IPB * Kn];        // [i][k], 1 KB
    __shared__ float w2_s[Kn];
    __shared__ float S[Ln * IPB];           // [j][i], 4 KB

    const int tid = threadIdx.x;
    const int b  = blockIdx.x / (Ln / IPB);
    const int i0 = (blockIdx.x % (Ln / IPB)) * IPB;

    if (tid < Kn) w2_s[tid] = W2[tid];
    {
        int ii = tid >> 6, kk = tid & 63;
        eq_s[ii * Kn + kk] = QK[(b * Ln + i0 + ii) * 128 + kk];
    }

    float ekr[Kn];
    const float4* kj4 = (const float4*)(QK + (b * Ln + tid) * 128 + 64);
    #pragma unroll
    for (int q = 0; q < 16; ++q) {
        float4 v = kj4[q];
        ekr[q * 4 + 0] = v.x; ekr[q * 4 + 1] = v.y;
        ekr[q * 4 + 2] = v.z; ekr[q * 4 + 3] = v.w;
    }
    __syncthreads();

    // Phase 1: T_i = sum_k w_k * rcp(Eq_ik*Ek_k + 1)
    float s[IPB] = {0, 0, 0, 0};
    const float4* w4  = (const float4*)w2_s;
    const float4* q4a = (const float4*)(eq_s);
    const float4* q4b = (const float4*)(eq_s + Kn);
    const float4* q4c = (const float4*)(eq_s + 2 * Kn);
    const float4* q4d = (const float4*)(eq_s + 3 * Kn);
    #pragma unroll
    for (int k4 = 0; k4 < 16; ++k4) {
        float4 w  = w4[k4];
        float4 q0 = q4a[k4], q1 = q4b[k4], q2 = q4c[k4], q3 = q4d[k4];
        #pragma unroll
        for (int c = 0; c < 4; ++c) {
            float ek = ekr[k4 * 4 + c];
            float wk = (c == 0) ? w.x : (c == 1) ? w.y : (c == 2) ? w.z : w.w;
            float e0 = (c == 0) ? q0.x : (c == 1) ? q0.y : (c == 2) ? q0.z : q0.w;
            float e1 = (c == 0) ? q1.x : (c == 1) ? q1.y : (c == 2) ? q1.z : q1.w;
            float e2 = (c == 0) ? q2.x : (c == 1) ? q2.y : (c == 2) ? q2.z : q2.w;
            float e3 = (c == 0) ? q3.x : (c == 1) ? q3.y : (c == 2) ? q3.z : q3.w;
            s[0] = fmaf(wk, __builtin_amdgcn_rcpf(fmaf(e0, ek, 1.0f)), s[0]);
            s[1] = fmaf(wk, __builtin_amdgcn_rcpf(fmaf(e1, ek, 1.0f)), s[1]);
            s[2] = fmaf(wk, __builtin_amdgcn_rcpf(fmaf(e2, ek, 1.0f)), s[2]);
            s[3] = fmaf(wk, __builtin_amdgcn_rcpf(fmaf(e3, ek, 1.0f)), s[3]);
        }
    }
    ((float4*)S)[tid] = make_float4(s[0], s[1], s[2], s[3]);   // S[j][i] = T
    __syncthreads();

    // Phase 2: softmax over j of (-2T). No max-subtract (|2T| <= ~13).
    // Wave wv owns row i=wv; stores attn row directly (coalesced b32 x4).
    {
        const int wv = tid >> 6, lane = tid & 63;
        float e0 = __expf(-2.0f * S[(lane      ) * IPB + wv]);
        float e1 = __expf(-2.0f * S[(lane +  64) * IPB + wv]);
        float e2 = __expf(-2.0f * S[(lane + 128) * IPB + wv]);
        float e3 = __expf(-2.0f * S[(lane + 192) * IPB + wv]);
        float sum = (e0 + e1) + (e2 + e3);
        #pragma unroll
        for (int off = 32; off > 0; off >>= 1)
            sum += __shfl_xor(sum, off);
        float inv = 1.0f / sum;
        float* arow = attn + (b * Ln + i0 + wv) * Ln;
        arow[lane      ] = e0 * inv;
        arow[lane +  64] = e1 * inv;
        arow[lane + 128] = e2 * inv;
        arow[lane + 192] = e3 * inv;
    }
}

// ---------------- K3: context = attn @ X, tiled ----------------
// grid = 8b x 8 i-tiles x 8 d-tiles = 512 blocks, 256 threads.
// Thread t: i = i0 + (t>>3), d-quad dq = t&7 (d = d0 + 4*dq .. +3).
__global__ __launch_bounds__(256) void ctx_kernel(
    const float* __restrict__ X,    // (2048,256)
    const float* __restrict__ attn, // (8,256,256)
    float* __restrict__ out)        // (2048,512)
{
    __shared__ float As[32 * ASTRIDE];   // attn tile [ii][j], ~33 KB

    const int tid = threadIdx.x;
    const int bid = blockIdx.x;
    const int b  = bid >> 6;
    const int it = (bid >> 3) & 7;       // i-tile
    const int dt = bid & 7;              // d-tile
    const int i0 = it * 32, d0 = dt * 32;

    // stage attn[b, i0:i0+32, :] -> As (2048 float4s, 8 per thread, coalesced)
    const float4* Ag4 = (const float4*)(attn + (b * Ln + i0) * Ln);
    #pragma unroll
    for (int q = 0; q < 8; ++q) {
        int idx = q * 256 + tid;         // 0..2047
        int row = idx >> 6, c4 = idx & 63;
        *((float4*)(As + row * ASTRIDE + c4 * 4)) = Ag4[idx];
    }
    __syncthreads();

    const int ii = tid >> 3, dq = tid & 7;
    const float* Arow = As + ii * ASTRIDE;
    const float4* Xb4 = (const float4*)(X + b * Ln * Dn) + (d0 >> 2) + dq;

    float4 c = {0.f, 0.f, 0.f, 0.f};
    #pragma unroll 4
    for (int j = 0; j < Ln; ++j) {
        float a  = Arow[j];              // LDS b32, 8 banks + broadcast
        float4 x = Xb4[j * 64];          // 128 B unique/wave, L1-dedup'd
        c.x = fmaf(a, x.x, c.x);
        c.y = fmaf(a, x.y, c.y);
        c.z = fmaf(a, x.z, c.z);
        c.w = fmaf(a, x.w, c.w);
    }

    const int row = b * Ln + i0 + ii;
    float4 xcopy = ((const float4*)(X + row * Dn))[(d0 >> 2) + dq];
    ((float4*)(out + row * 2 * Dn))[(d0 >> 2) + dq]      = xcopy;  // inputs half
    ((float4*)(out + row * 2 * Dn + Dn))[(d0 >> 2) + dq] = c;      // context half
}

extern "C" void kernel_launch(void* const* d_in, const int* in_sizes, int n_in,
                              void* d_out, int out_size, void* d_ws, size_t ws_size,
                              hipStream_t stream) {
    const float* X  = (const float*)d_in[0];   // (8,256,256)
    const float* W1 = (const float*)d_in[1];   // (64,512)
    const float* W2 = (const float*)d_in[2];   // (1,64)
    float* out = (float*)d_out;                // (8,256,512)

    float* QK   = (float*)d_ws;                           // 1 MB
    float* attn = (float*)((char*)d_ws + (1 << 20));      // 2 MB

    proj_kernel <<<ROWS / 4,  128, 0, stream>>>(X, W1, QK);
    score_kernel<<<ROWS / IPB, 256, 0, stream>>>(QK, W2, attn);
    ctx_kernel  <<<512,        256, 0, stream>>>(X, attn, out);
}

// Round 8
// 79.177 us; speedup vs baseline: 1.2539x; 1.2539x over previous
//
#include <hip/hip_runtime.h>

// SlotAttention: B=8, L=256, D=256, K=64
// out[b,i,:] = concat(inputs[b,i,:], context[b,i,:])
// scores[b,i,j] = sum_k W2[k]*tanh(qi+kj); attn = softmax_j; ctx = attn @ inputs[b]
//
// Round-8 = round-6 (best, 80.5 us) + softmax trims proven safe in round 7:
//   tanh(q+k) = 1 - 2/(Eq*Ek+1), Eq=e^{2q}, Ek=e^{2k}
//   score_i == const - 2*T_i; softmax is shift-invariant -> use -2T directly,
//   no Wsum, no max-subtract (|2T| <= 2*sum|w| ~= 13, exp can't overflow).
// Structure lessons: IPB=4 / 2 kernels is the optimum (R4 regs✗, R5 occ✗, R7 launch✗).

#define Bn 8
#define Ln 256
#define Dn 256
#define Kn 64
#define ROWS (Bn*Ln)       // 2048
#define IPB 4              // query rows per block in attn kernel

// ---------------- Kernel A: projection -> exp form ----------------
// QK[row][c]: c<64 -> Eq = e^{2*qi[k=c]}, c>=64 -> Ek = e^{2*kj[k=c-64]}
__global__ __launch_bounds__(128) void proj_kernel(
    const float* __restrict__ X,    // (2048,256)
    const float* __restrict__ W1,   // (64,512)
    float* __restrict__ QK)         // (2048,128)
{
    __shared__ float Xs[4 * 256];
    const int tid = threadIdx.x;
    const int r0 = blockIdx.x * 4;

    const float4* Xg4 = (const float4*)(X + r0 * Dn);
    float4* Xs4 = (float4*)Xs;
    #pragma unroll
    for (int idx = tid; idx < 256; idx += 128) Xs4[idx] = Xg4[idx];
    __syncthreads();

    const int k = tid & 63, half = tid >> 6;
    const float4* Wrow = (const float4*)(W1 + k * (2 * Dn) + half * Dn);
    float acc[4] = {0, 0, 0, 0};
    #pragma unroll 8
    for (int d4 = 0; d4 < 64; ++d4) {
        float4 w = Wrow[d4];
        #pragma unroll
        for (int r = 0; r < 4; ++r) {
            float4 x = ((const float4*)(Xs + r * Dn))[d4];  // uniform LDS broadcast
            float a = acc[r];
            a = fmaf(w.x, x.x, a);
            a = fmaf(w.y, x.y, a);
            a = fmaf(w.z, x.z, a);
            a = fmaf(w.w, x.w, a);
            acc[r] = a;
        }
    }
    #pragma unroll
    for (int r = 0; r < 4; ++r)
        QK[(r0 + r) * 128 + tid] = __expf(2.0f * acc[r]);   // Eq or Ek
}

// ---------------- Kernel B: scores + softmax + context ----------------
// grid = (B*L/IPB) blocks, 256 threads. Block handles rows i0..i0+3 of batch b.
__global__ __launch_bounds__(256) void attn_kernel(
    const float* __restrict__ X,    // (2048,256)
    const float* __restrict__ QK,   // (2048,128) exp'd
    const float* __restrict__ W2,   // (64,)
    float* __restrict__ out)        // (2048,512)
{
    __shared__ float eq_s[IPB * Kn];        // [i][k], 1 KB  (Eq values)
    __shared__ float w2_s[Kn];
    __shared__ float S[Ln * IPB];           // [j][i], 4 KB
    __shared__ float4 red[4 * IPB * 64];    // [wv][i][dquad], 16 KB

    const int tid = threadIdx.x;
    const int b  = blockIdx.x / (Ln / IPB);
    const int i0 = (blockIdx.x % (Ln / IPB)) * IPB;

    if (tid < Kn) w2_s[tid] = W2[tid];
    {   // Eq for the 4 query rows
        int ii = tid >> 6, kk = tid & 63;
        eq_s[ii * Kn + kk] = QK[(b * Ln + i0 + ii) * 128 + kk];
    }

    // thread owns key row j = tid: prefetch Ek row (64 floats) to registers
    float ekr[Kn];
    const float4* kj4 = (const float4*)(QK + (b * Ln + tid) * 128 + 64);
    #pragma unroll
    for (int q = 0; q < 16; ++q) {
        float4 v = kj4[q];
        ekr[q * 4 + 0] = v.x; ekr[q * 4 + 1] = v.y;
        ekr[q * 4 + 2] = v.z; ekr[q * 4 + 3] = v.w;
    }
    __syncthreads();

    // Phase 1: T_i = sum_k w_k * rcp(Eq_ik*Ek_k + 1); score used = -2T
    float s[IPB] = {0, 0, 0, 0};
    const float4* w4  = (const float4*)w2_s;
    const float4* q4a = (const float4*)(eq_s);
    const float4* q4b = (const float4*)(eq_s + Kn);
    const float4* q4c = (const float4*)(eq_s + 2 * Kn);
    const float4* q4d = (const float4*)(eq_s + 3 * Kn);
    #pragma unroll
    for (int k4 = 0; k4 < 16; ++k4) {
        float4 w  = w4[k4];
        float4 q0 = q4a[k4], q1 = q4b[k4], q2 = q4c[k4], q3 = q4d[k4];
        #pragma unroll
        for (int c = 0; c < 4; ++c) {
            float ek = ekr[k4 * 4 + c];
            float wk = (c == 0) ? w.x : (c == 1) ? w.y : (c == 2) ? w.z : w.w;
            float e0 = (c == 0) ? q0.x : (c == 1) ? q0.y : (c == 2) ? q0.z : q0.w;
            float e1 = (c == 0) ? q1.x : (c == 1) ? q1.y : (c == 2) ? q1.z : q1.w;
            float e2 = (c == 0) ? q2.x : (c == 1) ? q2.y : (c == 2) ? q2.z : q2.w;
            float e3 = (c == 0) ? q3.x : (c == 1) ? q3.y : (c == 2) ? q3.z : q3.w;
            s[0] = fmaf(wk, __builtin_amdgcn_rcpf(fmaf(e0, ek, 1.0f)), s[0]);
            s[1] = fmaf(wk, __builtin_amdgcn_rcpf(fmaf(e1, ek, 1.0f)), s[1]);
            s[2] = fmaf(wk, __builtin_amdgcn_rcpf(fmaf(e2, ek, 1.0f)), s[2]);
            s[3] = fmaf(wk, __builtin_amdgcn_rcpf(fmaf(e3, ek, 1.0f)), s[3]);
        }
    }
    ((float4*)S)[tid] = make_float4(s[0], s[1], s[2], s[3]);   // S[j][i] = T
    __syncthreads();

    // Phase 2: softmax over j of (-2T); wave wv owns row i=wv.
    // No max-subtract (|2T| <= ~13), no Wsum (shift-invariance).
    {
        const int wv = tid >> 6, lane = tid & 63;
        float e0 = __expf(-2.0f * S[(lane      ) * IPB + wv]);
        float e1 = __expf(-2.0f * S[(lane +  64) * IPB + wv]);
        float e2 = __expf(-2.0f * S[(lane + 128) * IPB + wv]);
        float e3 = __expf(-2.0f * S[(lane + 192) * IPB + wv]);
        float sum = (e0 + e1) + (e2 + e3);
        #pragma unroll
        for (int off = 32; off > 0; off >>= 1)
            sum += __shfl_xor(sum, off);
        float inv = 1.0f / sum;
        S[(lane      ) * IPB + wv] = e0 * inv;
        S[(lane +  64) * IPB + wv] = e1 * inv;
        S[(lane + 128) * IPB + wv] = e2 * inv;
        S[(lane + 192) * IPB + wv] = e3 * inv;
    }
    __syncthreads();

    // Phase 3: context, j split across waves; float4 X loads, LDS cross-wave reduce
    {
        const int wv = tid >> 6, lane = tid & 63;
        float4 acc0 = {0,0,0,0}, acc1 = {0,0,0,0}, acc2 = {0,0,0,0}, acc3 = {0,0,0,0};
        const float4* Xb4 = (const float4*)(X + b * Ln * Dn);
        const float4* S4  = (const float4*)S;
        const int jbase = wv * 64;
        #pragma unroll 8
        for (int jj = 0; jj < 64; ++jj) {
            int j = jbase + jj;
            float4 at = S4[j];                 // uniform broadcast b128
            float4 x  = Xb4[j * 64 + lane];    // coalesced 1 KB/wave
            acc0.x = fmaf(at.x, x.x, acc0.x); acc0.y = fmaf(at.x, x.y, acc0.y);
            acc0.z = fmaf(at.x, x.z, acc0.z); acc0.w = fmaf(at.x, x.w, acc0.w);
            acc1.x = fmaf(at.y, x.x, acc1.x); acc1.y = fmaf(at.y, x.y, acc1.y);
            acc1.z = fmaf(at.y, x.z, acc1.z); acc1.w = fmaf(at.y, x.w, acc1.w);
            acc2.x = fmaf(at.z, x.x, acc2.x); acc2.y = fmaf(at.z, x.y, acc2.y);
            acc2.z = fmaf(at.z, x.z, acc2.z); acc2.w = fmaf(at.z, x.w, acc2.w);
            acc3.x = fmaf(at.w, x.x, acc3.x); acc3.y = fmaf(at.w, x.y, acc3.y);
            acc3.z = fmaf(at.w, x.z, acc3.z); acc3.w = fmaf(at.w, x.w, acc3.w);
        }
        red[(wv * IPB + 0) * 64 + lane] = acc0;
        red[(wv * IPB + 1) * 64 + lane] = acc1;
        red[(wv * IPB + 2) * 64 + lane] = acc2;
        red[(wv * IPB + 3) * 64 + lane] = acc3;
    }
    __syncthreads();

    // Cross-wave reduce + b128 stores
    {
        const int i = tid >> 6, q = tid & 63;
        float4 p0 = red[(0 * IPB + i) * 64 + q];
        float4 p1 = red[(1 * IPB + i) * 64 + q];
        float4 p2 = red[(2 * IPB + i) * 64 + q];
        float4 p3 = red[(3 * IPB + i) * 64 + q];
        float4 c;
        c.x = (p0.x + p1.x) + (p2.x + p3.x);
        c.y = (p0.y + p1.y) + (p2.y + p3.y);
        c.z = (p0.z + p1.z) + (p2.z + p3.z);
        c.w = (p0.w + p1.w) + (p2.w + p3.w);
        const int row = b * Ln + i0 + i;
        float4 xcopy = ((const float4*)(X + row * Dn))[q];
        ((float4*)(out + row * 2 * Dn))[q]      = xcopy;  // inputs half
        ((float4*)(out + row * 2 * Dn + Dn))[q] = c;      // context half
    }
}

extern "C" void kernel_launch(void* const* d_in, const int* in_sizes, int n_in,
                              void* d_out, int out_size, void* d_ws, size_t ws_size,
                              hipStream_t stream) {
    const float* X  = (const float*)d_in[0];   // (8,256,256)
    const float* W1 = (const float*)d_in[1];   // (64,512)
    const float* W2 = (const float*)d_in[2];   // (1,64)
    float* out = (float*)d_out;                // (8,256,512)
    float* QK  = (float*)d_ws;                 // (2048,128) = 1 MB scratch

    proj_kernel<<<ROWS / 4, 128, 0, stream>>>(X, W1, QK);
    attn_kernel<<<ROWS / IPB, 256, 0, stream>>>(X, QK, W2, out);
}